// Round 12
// baseline (93.431 us; speedup 1.0000x reference)
//
#include <hip/hip_runtime.h>
#include <stdint.h>

typedef __attribute__((ext_vector_type(8))) short short8;
typedef __attribute__((ext_vector_type(4))) float f32x4;

#define HASH_SIZE 65536
#define HASH_MASK (HASH_SIZE - 1)
#define EMPTY_KEY 0xFFFFFFFFFFFFFFFFull
#define BIASF 256.0f
#define POS_T 0.1f
#define NEG_T 1.4f

__device__ __forceinline__ unsigned bf16rne(float f) {
  unsigned u = __builtin_bit_cast(unsigned, f);
  return (u + 0x7FFFu + ((u >> 16) & 1u)) >> 16;
}

__device__ __forceinline__ unsigned hash_of(unsigned long long key) {
  return (unsigned)((key * 0x9E3779B97F4A7C15ull) >> 48) & HASH_MASK;
}

__device__ __forceinline__ unsigned umin32(unsigned a, unsigned b) { return a < b ? a : b; }
__device__ __forceinline__ unsigned umin3(unsigned a, unsigned b, unsigned c) {
  return umin32(a, umin32(b, c));  // v_min3_u32
}

__device__ __forceinline__ bool hash_contains(const unsigned long long* __restrict__ tab,
                                              unsigned long long key) {
  unsigned h = hash_of(key);
  while (true) {
    unsigned long long v = tab[h];
    if (v == key) return true;
    if (v == EMPTY_KEY) return false;
    h = (h + 1) & HASH_MASK;
  }
}

// Fill mp0|mp1|table (contiguous) with 0xFF; zero accum+ticket via stride loop.
__global__ __launch_bounds__(256) void init_ws(uint4* __restrict__ fillbase, int nvec4,
                                               unsigned* __restrict__ zerobase, int nzero) {
  int i = blockIdx.x * 256 + threadIdx.x;
  if (i < nvec4) fillbase[i] = make_uint4(~0u, ~0u, ~0u, ~0u);
  if (blockIdx.x == 0) {
    for (int z = threadIdx.x; z < nzero; z += 256) zerobase[z] = 0u;
  }
}

// Fused gather, 64-thread blocks. Blocks [0,P/64): pos pairs; then M/64 each for subs.
__global__ __launch_bounds__(64) void gather_all(
    const float* __restrict__ F0, const float* __restrict__ F1,
    const int* __restrict__ matches, const int* __restrict__ sel0,
    const int* __restrict__ sel1,
    unsigned* __restrict__ posA, unsigned* __restrict__ posB,
    unsigned* __restrict__ subA, unsigned* __restrict__ subB,
    float* __restrict__ rn0, float* __restrict__ rn1,
    float* __restrict__ cnb0, float* __restrict__ cnb1,
    unsigned long long* __restrict__ table, float* __restrict__ accum,
    long long hash_seed, int P, int M) {
  int nPosB = P / 64;
  int nSubB = M / 64;
  int bx = blockIdx.x;
  if (bx < nPosB) {
    int p = bx * 64 + threadIdx.x;
    int i0 = matches[2 * p];
    int i1 = matches[2 * p + 1];
    const float4* a4 = (const float4*)(F0 + (size_t)i0 * 32);
    const float4* b4 = (const float4*)(F1 + (size_t)i1 * 32);
    float na = 0.f, nb = 0.f, dd = 0.f;
    uint4 pa[4], pb[4];
#pragma unroll
    for (int k = 0; k < 4; k++) {
      float4 a0 = a4[2 * k], a1 = a4[2 * k + 1];
      float4 b0 = b4[2 * k], b1 = b4[2 * k + 1];
      na += a0.x * a0.x + a0.y * a0.y + a0.z * a0.z + a0.w * a0.w;
      na += a1.x * a1.x + a1.y * a1.y + a1.z * a1.z + a1.w * a1.w;
      nb += b0.x * b0.x + b0.y * b0.y + b0.z * b0.z + b0.w * b0.w;
      nb += b1.x * b1.x + b1.y * b1.y + b1.z * b1.z + b1.w * b1.w;
      float dx;
      dx = a0.x - b0.x; dd += dx * dx;
      dx = a0.y - b0.y; dd += dx * dx;
      dx = a0.z - b0.z; dd += dx * dx;
      dx = a0.w - b0.w; dd += dx * dx;
      dx = a1.x - b1.x; dd += dx * dx;
      dx = a1.y - b1.y; dd += dx * dx;
      dx = a1.z - b1.z; dd += dx * dx;
      dx = a1.w - b1.w; dd += dx * dx;
      pa[k].x = (bf16rne(a0.y) << 16) | bf16rne(a0.x);
      pa[k].y = (bf16rne(a0.w) << 16) | bf16rne(a0.z);
      pa[k].z = (bf16rne(a1.y) << 16) | bf16rne(a1.x);
      pa[k].w = (bf16rne(a1.w) << 16) | bf16rne(a1.z);
      pb[k].x = (bf16rne(b0.y) << 16) | bf16rne(b0.x);
      pb[k].y = (bf16rne(b0.w) << 16) | bf16rne(b0.z);
      pb[k].z = (bf16rne(b1.y) << 16) | bf16rne(b1.x);
      pb[k].w = (bf16rne(b1.w) << 16) | bf16rne(b1.z);
    }
    uint4* dA = (uint4*)(posA + (size_t)p * 16);
    uint4* dB = (uint4*)(posB + (size_t)p * 16);
#pragma unroll
    for (int k = 0; k < 4; k++) { dA[k] = pa[k]; dB[k] = pb[k]; }
    rn0[p] = na;
    rn1[p] = nb;
    float ploss = fmaxf(dd - POS_T, 0.f);
    unsigned long long key =
        (unsigned long long)i0 + (unsigned long long)i1 * (unsigned long long)hash_seed;
    unsigned h = hash_of(key);
    while (true) {
      unsigned long long prev = atomicCAS(&table[h], EMPTY_KEY, key);
      if (prev == EMPTY_KEY || prev == key) break;
      h = (h + 1) & HASH_MASK;
    }
    for (int m = 32; m >= 1; m >>= 1) ploss += __shfl_down(ploss, m, 64);
    if (threadIdx.x == 0) atomicAdd(&accum[0], ploss);
  } else {
    bool second = (bx >= nPosB + nSubB);
    int m = (bx - nPosB - (second ? nSubB : 0)) * 64 + threadIdx.x;
    const float* F = second ? F1 : F0;
    const int* sel = second ? sel1 : sel0;
    unsigned* dst = second ? subB : subA;
    float* cnb = second ? cnb1 : cnb0;
    int j = sel[m];
    const float4* a4 = (const float4*)(F + (size_t)j * 32);
    float n = 0.f;
    uint4 pa[4];
#pragma unroll
    for (int k = 0; k < 4; k++) {
      float4 a0 = a4[2 * k], a1 = a4[2 * k + 1];
      n += a0.x * a0.x + a0.y * a0.y + a0.z * a0.z + a0.w * a0.w;
      n += a1.x * a1.x + a1.y * a1.y + a1.z * a1.z + a1.w * a1.w;
      pa[k].x = (bf16rne(a0.y) << 16) | bf16rne(a0.x);
      pa[k].y = (bf16rne(a0.w) << 16) | bf16rne(a0.z);
      pa[k].z = (bf16rne(a1.y) << 16) | bf16rne(a1.x);
      pa[k].w = (bf16rne(a1.w) << 16) | bf16rne(a1.z);
    }
    uint4* d4 = (uint4*)(dst + (size_t)m * 16);
#pragma unroll
    for (int k = 0; k < 4; k++) d4[k] = pa[k];
    cnb[m] = n + BIASF;
  }
}

// LDS-staged minkernel, v2 (fixing R11's two failures):
//   - write-immediately staging: stage regs live only inside the staging phase
//     (R11 held them across compute -> VGPR 120, occupancy 17.7%)
//   - LINEAR [col][16w] LDS layout, no pad: 64B col stride -> wave's b128 read is
//     64 dense distinct 16B slots (2-way class, free per m136). R11's 20-word pad
//     CAUSED the 2.1M conflicts.
// LDS 17KB -> 8 blocks/CU (136KB), 32 waves/CU kept. Inner loop has zero global loads.
__global__ __launch_bounds__(256) void minkernel(
    const unsigned* __restrict__ posA, const unsigned* __restrict__ posB,
    const unsigned* __restrict__ subA, const unsigned* __restrict__ subB,
    const float* __restrict__ cnb0, const float* __restrict__ cnb1,
    unsigned* __restrict__ mp0, unsigned* __restrict__ mp1, int halfgrid) {
  __shared__ unsigned lds_b[256 * 16];
  __shared__ float lds_c[256];

  int bx = blockIdx.x;
  bool dir = bx >= halfgrid;
  if (dir) bx -= halfgrid;
  const unsigned* rowfeat = dir ? posB : posA;
  const unsigned* colfeat = dir ? subA : subB;
  const float* cnb = dir ? cnb0 : cnb1;
  unsigned* outpacked = dir ? mp1 : mp0;

  int rowGroup = bx >> 3;
  int chunk = bx & 7;
  int lane = threadIdx.x & 63;
  int wave = threadIdx.x >> 6;
  int rowbase = rowGroup * 128 + wave * 32;
  int l15 = lane & 15;
  int khi = lane >> 4;
  int t = threadIdx.x;

  const unsigned* rf = rowfeat + (size_t)(rowbase + l15) * 16 + khi * 4;
  short8 a0 = *(const short8*)(rf + 0);
  short8 a1 = *(const short8*)(rf + 256);

  unsigned pm0[4] = {~0u, ~0u, ~0u, ~0u};
  unsigned pm1[4] = {~0u, ~0u, ~0u, ~0u};

  int colbase = chunk * 1024;

  for (int s = 0; s < 4; s++) {
    __syncthreads();  // previous stage's compute done; buffer reusable
    {
      // thread t stages col (s*256 + t): 64B features + 1 float norm
      const uint4* src = (const uint4*)(colfeat + (size_t)(colbase + s * 256 + t) * 16);
      uint4 q0 = src[0], q1 = src[1], q2 = src[2], q3 = src[3];
      float cv = cnb[colbase + s * 256 + t];
      uint4* dst = (uint4*)(lds_b + t * 16);
      dst[0] = q0; dst[1] = q1; dst[2] = q2; dst[3] = q3;
      lds_c[t] = cv;
    }
    __syncthreads();  // stage visible to all waves

#pragma unroll
    for (int ctp = 0; ctp < 8; ctp++) {  // 8 tile-pairs = 16 col-tiles per stage
      int colA = ctp * 32 + l15;
      short8 bA = *(const short8*)(lds_b + colA * 16 + khi * 4);
      short8 bB = *(const short8*)(lds_b + (colA + 16) * 16 + khi * 4);
      float cA = lds_c[colA];
      float cB = lds_c[colA + 16];
      unsigned iA = (unsigned)(colbase + s * 256 + ctp * 32 + l15);
      unsigned iB = iA + 16;
      f32x4 z = {0.f, 0.f, 0.f, 0.f};
      f32x4 aA0 = __builtin_amdgcn_mfma_f32_16x16x32_bf16(a0, bA, z, 0, 0, 0);
      f32x4 aA1 = __builtin_amdgcn_mfma_f32_16x16x32_bf16(a1, bA, z, 0, 0, 0);
      f32x4 aB0 = __builtin_amdgcn_mfma_f32_16x16x32_bf16(a0, bB, z, 0, 0, 0);
      f32x4 aB1 = __builtin_amdgcn_mfma_f32_16x16x32_bf16(a1, bB, z, 0, 0, 0);
#pragma unroll
      for (int r = 0; r < 4; r++) {
        float tA0 = fmaf(-2.f, aA0[r], cA);
        float tB0 = fmaf(-2.f, aB0[r], cB);
        unsigned kA0 = (__builtin_bit_cast(unsigned, tA0) & 0xFFFFE000u) | iA;
        unsigned kB0 = (__builtin_bit_cast(unsigned, tB0) & 0xFFFFE000u) | iB;
        pm0[r] = umin3(pm0[r], kA0, kB0);
        float tA1 = fmaf(-2.f, aA1[r], cA);
        float tB1 = fmaf(-2.f, aB1[r], cB);
        unsigned kA1 = (__builtin_bit_cast(unsigned, tA1) & 0xFFFFE000u) | iA;
        unsigned kB1 = (__builtin_bit_cast(unsigned, tB1) & 0xFFFFE000u) | iB;
        pm1[r] = umin3(pm1[r], kA1, kB1);
      }
    }
  }

#pragma unroll
  for (int r = 0; r < 4; r++) {
#pragma unroll
    for (int m = 8; m >= 1; m >>= 1) {
      pm0[r] = umin32(pm0[r], (unsigned)__shfl_xor((int)pm0[r], m, 64));
      pm1[r] = umin32(pm1[r], (unsigned)__shfl_xor((int)pm1[r], m, 64));
    }
  }
  if (l15 == 0) {
#pragma unroll
    for (int r = 0; r < 4; r++) {
      atomicMin(&outpacked[rowbase + khi * 4 + r], pm0[r]);
      atomicMin(&outpacked[rowbase + 16 + khi * 4 + r], pm1[r]);
    }
  }
}

// Separate finalize, 64-thread blocks (256 blocks) + last-block combine via ticket.
__global__ __launch_bounds__(64) void finalize(
    const unsigned* __restrict__ mp0, const unsigned* __restrict__ mp1,
    const float* __restrict__ rn0, const float* __restrict__ rn1,
    const int* __restrict__ matches, const int* __restrict__ sel0,
    const int* __restrict__ sel1, const unsigned long long* __restrict__ table,
    float* __restrict__ accum, unsigned* __restrict__ ticket,
    float* __restrict__ out, long long hash_seed, int P) {
  int p = blockIdx.x * 64 + threadIdx.x;
  float s0 = 0.f, c0 = 0.f, s1 = 0.f, c1 = 0.f;
  {
    int i0 = matches[2 * p];
    int i1 = matches[2 * p + 1];
    {
      unsigned k = mp0[p];
      float t = __builtin_bit_cast(float, k & 0xFFFFE000u);
      float d2 = t - BIASF + rn0[p];
      float d = sqrtf(fmaxf(d2, 0.f) + 1e-7f);
      float rl = fmaxf(NEG_T - d, 0.f);
      int j = (int)(k & 0x1FFFu);
      long long ind = sel1[j];
      unsigned long long nk =
          (unsigned long long)i0 + (unsigned long long)ind * (unsigned long long)hash_seed;
      float msk = hash_contains(table, nk) ? 0.f : 1.f;
      s0 = rl * rl * msk;
      c0 = msk;
    }
    {
      unsigned k = mp1[p];
      float t = __builtin_bit_cast(float, k & 0xFFFFE000u);
      float d2 = t - BIASF + rn1[p];
      float d = sqrtf(fmaxf(d2, 0.f) + 1e-7f);
      float rl = fmaxf(NEG_T - d, 0.f);
      int j = (int)(k & 0x1FFFu);
      long long ind = sel0[j];
      unsigned long long nk =
          (unsigned long long)ind + (unsigned long long)i1 * (unsigned long long)hash_seed;
      float msk = hash_contains(table, nk) ? 0.f : 1.f;
      s1 = rl * rl * msk;
      c1 = msk;
    }
  }
  for (int m = 32; m >= 1; m >>= 1) {
    s0 += __shfl_down(s0, m, 64);
    c0 += __shfl_down(c0, m, 64);
    s1 += __shfl_down(s1, m, 64);
    c1 += __shfl_down(c1, m, 64);
  }
  if (threadIdx.x == 0) {
    atomicAdd(&accum[1], s0);
    atomicAdd(&accum[2], c0);
    atomicAdd(&accum[3], s1);
    atomicAdd(&accum[4], c1);
    __threadfence();
    unsigned done = atomicAdd(ticket, 1u);
    if (done == gridDim.x - 1) {
      __threadfence();
      float pos = accum[0] / (float)P;
      float n0 = accum[1] / fmaxf(accum[2], 1.f);
      float n1 = accum[3] / fmaxf(accum[4], 1.f);
      out[0] = pos + 0.5f * (n0 + n1);
    }
  }
}

extern "C" void kernel_launch(void* const* d_in, const int* in_sizes, int n_in,
                              void* d_out, int out_size, void* d_ws, size_t ws_size,
                              hipStream_t stream) {
  const float* F0 = (const float*)d_in[0];
  const float* F1 = (const float*)d_in[1];
  const int* matches = (const int*)d_in[2];
  const int* sel0 = (const int*)d_in[3];
  const int* sel1 = (const int*)d_in[4];

  int N0 = in_sizes[0] / 32;
  int N1 = in_sizes[1] / 32;
  long long hash_seed = (long long)(N0 > N1 ? N0 : N1);  // 100000
  int P = in_sizes[2] / 2;  // 16384
  int M = in_sizes[3];      // 8192

  unsigned* posA = (unsigned*)d_ws;            // [P][16] u32 (bf16 pairs)
  unsigned* posB = posA + (size_t)P * 16;
  unsigned* subA = posB + (size_t)P * 16;      // [M][16]
  unsigned* subB = subA + (size_t)M * 16;
  float* rn0 = (float*)(subB + (size_t)M * 16);
  float* rn1 = rn0 + P;
  float* cnb0 = rn1 + P;
  float* cnb1 = cnb0 + M;
  unsigned* mp0 = (unsigned*)(cnb1 + M);       // ---- 0xFF fill region start
  unsigned* mp1 = mp0 + P;
  unsigned long long* table = (unsigned long long*)(mp1 + P);
  float* accum = (float*)(table + HASH_SIZE);  // ---- zero region
  unsigned* ticket = (unsigned*)(accum + 8);

  int fillWords = 2 * P + 2 * HASH_SIZE;  // u32 words in 0xFF region
  int nvec4 = fillWords / 4;
  int nzero = 16;  // accum(8) + ticket(1) + pad
  init_ws<<<(nvec4 + 255) / 256, 256, 0, stream>>>((uint4*)mp0, nvec4, (unsigned*)accum, nzero);

  int nPosB = P / 64, nSubB = M / 64;
  gather_all<<<nPosB + 2 * nSubB, 64, 0, stream>>>(
      F0, F1, matches, sel0, sel1, posA, posB, subA, subB, rn0, rn1, cnb0, cnb1,
      table, accum, hash_seed, P, M);

  int halfgrid = (P / 128) * 8;  // 1024
  minkernel<<<2 * halfgrid, 256, 0, stream>>>(posA, posB, subA, subB, cnb0, cnb1,
                                              mp0, mp1, halfgrid);

  finalize<<<P / 64, 64, 0, stream>>>(mp0, mp1, rn0, rn1, matches, sel0, sel1,
                                      table, accum, ticket, (float*)d_out, hash_seed, P);
}

// Round 13
// 71.560 us; speedup vs baseline: 1.3056x; 1.3056x over previous
//
#include <hip/hip_runtime.h>
#include <stdint.h>

typedef __attribute__((ext_vector_type(8))) short short8;
typedef __attribute__((ext_vector_type(4))) float f32x4;

#define HASH_SIZE 65536
#define HASH_MASK (HASH_SIZE - 1)
#define EMPTY_KEY 0xFFFFFFFFFFFFFFFFull
#define BIASF 256.0f
#define POS_T 0.1f
#define NEG_T 1.4f

__device__ __forceinline__ unsigned bf16rne(float f) {
  unsigned u = __builtin_bit_cast(unsigned, f);
  return (u + 0x7FFFu + ((u >> 16) & 1u)) >> 16;
}

__device__ __forceinline__ unsigned hash_of(unsigned long long key) {
  return (unsigned)((key * 0x9E3779B97F4A7C15ull) >> 48) & HASH_MASK;
}

__device__ __forceinline__ unsigned umin32(unsigned a, unsigned b) { return a < b ? a : b; }
__device__ __forceinline__ unsigned umin3(unsigned a, unsigned b, unsigned c) {
  return umin32(a, umin32(b, c));  // v_min3_u32
}

__device__ __forceinline__ bool hash_contains(const unsigned long long* __restrict__ tab,
                                              unsigned long long key) {
  unsigned h = hash_of(key);
  while (true) {
    unsigned long long v = tab[h];
    if (v == key) return true;
    if (v == EMPTY_KEY) return false;
    h = (h + 1) & HASH_MASK;
  }
}

// wave-level release: drain this wave's outstanding VMEM (atomics included) WITHOUT
// the L2-writeback that __threadfence() emits. Atomics are device-coherent once
// retired (m20), so vmcnt(0) + atomic ticket is a valid release on gfx950.
__device__ __forceinline__ void wave_release() {
  asm volatile("s_waitcnt vmcnt(0)" ::: "memory");
}

// Fill mp0|mp1|table (contiguous) with 0xFF; zero accum+tickets+donecnt via stride loop.
__global__ __launch_bounds__(256) void init_ws(uint4* __restrict__ fillbase, int nvec4,
                                               unsigned* __restrict__ zerobase, int nzero) {
  int i = blockIdx.x * 256 + threadIdx.x;
  if (i < nvec4) fillbase[i] = make_uint4(~0u, ~0u, ~0u, ~0u);
  if (blockIdx.x == 0) {
    for (int z = threadIdx.x; z < nzero; z += 256) zerobase[z] = 0u;
  }
}

// Fused gather, 64-thread blocks. Blocks [0,P/64): pos pairs; then M/64 each for subs.
__global__ __launch_bounds__(64) void gather_all(
    const float* __restrict__ F0, const float* __restrict__ F1,
    const int* __restrict__ matches, const int* __restrict__ sel0,
    const int* __restrict__ sel1,
    unsigned* __restrict__ posA, unsigned* __restrict__ posB,
    unsigned* __restrict__ subA, unsigned* __restrict__ subB,
    float* __restrict__ rn0, float* __restrict__ rn1,
    float* __restrict__ cnb0, float* __restrict__ cnb1,
    unsigned long long* __restrict__ table, float* __restrict__ accum,
    long long hash_seed, int P, int M) {
  int nPosB = P / 64;
  int nSubB = M / 64;
  int bx = blockIdx.x;
  if (bx < nPosB) {
    int p = bx * 64 + threadIdx.x;
    int i0 = matches[2 * p];
    int i1 = matches[2 * p + 1];
    const float4* a4 = (const float4*)(F0 + (size_t)i0 * 32);
    const float4* b4 = (const float4*)(F1 + (size_t)i1 * 32);
    float na = 0.f, nb = 0.f, dd = 0.f;
    uint4 pa[4], pb[4];
#pragma unroll
    for (int k = 0; k < 4; k++) {
      float4 a0 = a4[2 * k], a1 = a4[2 * k + 1];
      float4 b0 = b4[2 * k], b1 = b4[2 * k + 1];
      na += a0.x * a0.x + a0.y * a0.y + a0.z * a0.z + a0.w * a0.w;
      na += a1.x * a1.x + a1.y * a1.y + a1.z * a1.z + a1.w * a1.w;
      nb += b0.x * b0.x + b0.y * b0.y + b0.z * b0.z + b0.w * b0.w;
      nb += b1.x * b1.x + b1.y * b1.y + b1.z * b1.z + b1.w * b1.w;
      float dx;
      dx = a0.x - b0.x; dd += dx * dx;
      dx = a0.y - b0.y; dd += dx * dx;
      dx = a0.z - b0.z; dd += dx * dx;
      dx = a0.w - b0.w; dd += dx * dx;
      dx = a1.x - b1.x; dd += dx * dx;
      dx = a1.y - b1.y; dd += dx * dx;
      dx = a1.z - b1.z; dd += dx * dx;
      dx = a1.w - b1.w; dd += dx * dx;
      pa[k].x = (bf16rne(a0.y) << 16) | bf16rne(a0.x);
      pa[k].y = (bf16rne(a0.w) << 16) | bf16rne(a0.z);
      pa[k].z = (bf16rne(a1.y) << 16) | bf16rne(a1.x);
      pa[k].w = (bf16rne(a1.w) << 16) | bf16rne(a1.z);
      pb[k].x = (bf16rne(b0.y) << 16) | bf16rne(b0.x);
      pb[k].y = (bf16rne(b0.w) << 16) | bf16rne(b0.z);
      pb[k].z = (bf16rne(b1.y) << 16) | bf16rne(b1.x);
      pb[k].w = (bf16rne(b1.w) << 16) | bf16rne(b1.z);
    }
    uint4* dA = (uint4*)(posA + (size_t)p * 16);
    uint4* dB = (uint4*)(posB + (size_t)p * 16);
#pragma unroll
    for (int k = 0; k < 4; k++) { dA[k] = pa[k]; dB[k] = pb[k]; }
    rn0[p] = na;
    rn1[p] = nb;
    float ploss = fmaxf(dd - POS_T, 0.f);
    unsigned long long key =
        (unsigned long long)i0 + (unsigned long long)i1 * (unsigned long long)hash_seed;
    unsigned h = hash_of(key);
    while (true) {
      unsigned long long prev = atomicCAS(&table[h], EMPTY_KEY, key);
      if (prev == EMPTY_KEY || prev == key) break;
      h = (h + 1) & HASH_MASK;
    }
    for (int m = 32; m >= 1; m >>= 1) ploss += __shfl_down(ploss, m, 64);
    if (threadIdx.x == 0) atomicAdd(&accum[0], ploss);
  } else {
    bool second = (bx >= nPosB + nSubB);
    int m = (bx - nPosB - (second ? nSubB : 0)) * 64 + threadIdx.x;
    const float* F = second ? F1 : F0;
    const int* sel = second ? sel1 : sel0;
    unsigned* dst = second ? subB : subA;
    float* cnb = second ? cnb1 : cnb0;
    int j = sel[m];
    const float4* a4 = (const float4*)(F + (size_t)j * 32);
    float n = 0.f;
    uint4 pa[4];
#pragma unroll
    for (int k = 0; k < 4; k++) {
      float4 a0 = a4[2 * k], a1 = a4[2 * k + 1];
      n += a0.x * a0.x + a0.y * a0.y + a0.z * a0.z + a0.w * a0.w;
      n += a1.x * a1.x + a1.y * a1.y + a1.z * a1.z + a1.w * a1.w;
      pa[k].x = (bf16rne(a0.y) << 16) | bf16rne(a0.x);
      pa[k].y = (bf16rne(a0.w) << 16) | bf16rne(a0.z);
      pa[k].z = (bf16rne(a1.y) << 16) | bf16rne(a1.x);
      pa[k].w = (bf16rne(a1.w) << 16) | bf16rne(a1.z);
    }
    uint4* d4 = (uint4*)(dst + (size_t)m * 16);
#pragma unroll
    for (int k = 0; k < 4; k++) d4[k] = pa[k];
    cnb[m] = n + BIASF;
  }
}

// R8 minkernel (46.2µs inner loop, byte-identical) + fused ticket finalize with
// vmcnt-release instead of __threadfence (R5-7's fence storm = +55µs; atomics are
// device-coherent once vmcnt-retired, so no L2 writeback needed).
__global__ __launch_bounds__(256) void minkernel(
    const unsigned* __restrict__ posA, const unsigned* __restrict__ posB,
    const unsigned* __restrict__ subA, const unsigned* __restrict__ subB,
    const float* __restrict__ cnb0, const float* __restrict__ cnb1,
    const float* __restrict__ rn0, const float* __restrict__ rn1,
    const int* __restrict__ matches, const int* __restrict__ sel0,
    const int* __restrict__ sel1, const unsigned long long* __restrict__ table,
    unsigned* __restrict__ mp0, unsigned* __restrict__ mp1,
    float* __restrict__ accum, unsigned* __restrict__ tickets,
    unsigned* __restrict__ donecnt, float* __restrict__ out,
    long long hash_seed, int halfgrid, int P) {
  int bx = blockIdx.x;
  int dir = bx >= halfgrid ? 1 : 0;
  if (dir) bx -= halfgrid;
  const unsigned* rowfeat = dir ? posB : posA;
  const unsigned* colfeat = dir ? subA : subB;
  const float* cnb = dir ? cnb0 : cnb1;
  unsigned* outp = dir ? mp1 : mp0;

  int rg = bx >> 3;
  int chunk = bx & 7;
  int lane = threadIdx.x & 63;
  int wave = threadIdx.x >> 6;
  int rowbase = rg * 128 + wave * 32;
  int l15 = lane & 15;
  int khi = lane >> 4;

  const unsigned* rf = rowfeat + (size_t)(rowbase + l15) * 16 + khi * 4;
  short8 a0 = *(const short8*)(rf + 0);
  short8 a1 = *(const short8*)(rf + 256);

  unsigned pm0[4] = {~0u, ~0u, ~0u, ~0u};
  unsigned pm1[4] = {~0u, ~0u, ~0u, ~0u};

  int colbase = chunk * 1024;
  const unsigned* cf = colfeat + (size_t)(colbase + l15) * 16 + khi * 4;
  const float* cn = cnb + colbase + l15;
  unsigned cidx = (unsigned)(colbase + l15);

  for (int pt = 0; pt < 32; pt++) {  // 32 pairs = 64 col-tiles
    short8 bA = *(const short8*)(cf);
    short8 bB = *(const short8*)(cf + 256);
    float cA = cn[0];
    float cB = cn[16];
    unsigned iA = cidx;
    unsigned iB = cidx + 16;
    f32x4 z = {0.f, 0.f, 0.f, 0.f};
    f32x4 aA0 = __builtin_amdgcn_mfma_f32_16x16x32_bf16(a0, bA, z, 0, 0, 0);
    f32x4 aA1 = __builtin_amdgcn_mfma_f32_16x16x32_bf16(a1, bA, z, 0, 0, 0);
    f32x4 aB0 = __builtin_amdgcn_mfma_f32_16x16x32_bf16(a0, bB, z, 0, 0, 0);
    f32x4 aB1 = __builtin_amdgcn_mfma_f32_16x16x32_bf16(a1, bB, z, 0, 0, 0);
#pragma unroll
    for (int r = 0; r < 4; r++) {
      float tA0 = fmaf(-2.f, aA0[r], cA);
      float tB0 = fmaf(-2.f, aB0[r], cB);
      unsigned kA0 = (__builtin_bit_cast(unsigned, tA0) & 0xFFFFE000u) | iA;
      unsigned kB0 = (__builtin_bit_cast(unsigned, tB0) & 0xFFFFE000u) | iB;
      pm0[r] = umin3(pm0[r], kA0, kB0);
      float tA1 = fmaf(-2.f, aA1[r], cA);
      float tB1 = fmaf(-2.f, aB1[r], cB);
      unsigned kA1 = (__builtin_bit_cast(unsigned, tA1) & 0xFFFFE000u) | iA;
      unsigned kB1 = (__builtin_bit_cast(unsigned, tB1) & 0xFFFFE000u) | iB;
      pm1[r] = umin3(pm1[r], kA1, kB1);
    }
    cf += 512;
    cn += 32;
    cidx += 32;
  }

#pragma unroll
  for (int r = 0; r < 4; r++) {
#pragma unroll
    for (int m = 8; m >= 1; m >>= 1) {
      pm0[r] = umin32(pm0[r], (unsigned)__shfl_xor((int)pm0[r], m, 64));
      pm1[r] = umin32(pm1[r], (unsigned)__shfl_xor((int)pm1[r], m, 64));
    }
  }
  if (l15 == 0) {
#pragma unroll
    for (int r = 0; r < 4; r++) {
      atomicMin(&outp[rowbase + khi * 4 + r], pm0[r]);
      atomicMin(&outp[rowbase + 16 + khi * 4 + r], pm1[r]);
    }
  }

  // ---- fused finalize: vmcnt-release ticket (NO __threadfence) ----
  __shared__ unsigned sdone;
  wave_release();      // this wave's atomicMins retired at device coherence point
  __syncthreads();     // all 4 waves released
  if (threadIdx.x == 0) sdone = atomicAdd(&tickets[dir * 128 + rg], 1u);
  __syncthreads();
  if (sdone == 7u) {   // 8th chunk-block of this (dir, rg): finalize its 128 rows
    float s = 0.f, c = 0.f;
    if (threadIdx.x < 128) {
      int p = rg * 128 + threadIdx.x;
      unsigned k = atomicMin(&outp[p], ~0u);  // atomic read: L1-bypass, coherent
      float t = __builtin_bit_cast(float, k & 0xFFFFE000u);
      float rnv = dir ? rn1[p] : rn0[p];
      float d2 = t - BIASF + rnv;
      float d = sqrtf(fmaxf(d2, 0.f) + 1e-7f);
      float rl = fmaxf(NEG_T - d, 0.f);
      int j = (int)(k & 0x1FFFu);
      int i0 = matches[2 * p];
      int i1 = matches[2 * p + 1];
      unsigned long long nk;
      if (dir) {
        long long ind = sel0[j];
        nk = (unsigned long long)ind + (unsigned long long)i1 * (unsigned long long)hash_seed;
      } else {
        long long ind = sel1[j];
        nk = (unsigned long long)i0 + (unsigned long long)ind * (unsigned long long)hash_seed;
      }
      float msk = hash_contains(table, nk) ? 0.f : 1.f;
      s = rl * rl * msk;
      c = msk;
    }
    for (int m = 32; m >= 1; m >>= 1) {
      s += __shfl_down(s, m, 64);
      c += __shfl_down(c, m, 64);
    }
    if ((threadIdx.x & 63) == 0 && threadIdx.x < 128) {
      atomicAdd(&accum[1 + 2 * dir], s);
      atomicAdd(&accum[2 + 2 * dir], c);
    }
    wave_release();
    __syncthreads();
    if (threadIdx.x == 0) {
      unsigned dn = atomicAdd(donecnt, 1u);
      if (dn == 255u) {
        float pos = atomicAdd(&accum[0], 0.f) / (float)P;
        float s0 = atomicAdd(&accum[1], 0.f);
        float c0 = atomicAdd(&accum[2], 0.f);
        float s1 = atomicAdd(&accum[3], 0.f);
        float c1 = atomicAdd(&accum[4], 0.f);
        float n0 = s0 / fmaxf(c0, 1.f);
        float n1 = s1 / fmaxf(c1, 1.f);
        out[0] = pos + 0.5f * (n0 + n1);
      }
    }
  }
}

extern "C" void kernel_launch(void* const* d_in, const int* in_sizes, int n_in,
                              void* d_out, int out_size, void* d_ws, size_t ws_size,
                              hipStream_t stream) {
  const float* F0 = (const float*)d_in[0];
  const float* F1 = (const float*)d_in[1];
  const int* matches = (const int*)d_in[2];
  const int* sel0 = (const int*)d_in[3];
  const int* sel1 = (const int*)d_in[4];

  int N0 = in_sizes[0] / 32;
  int N1 = in_sizes[1] / 32;
  long long hash_seed = (long long)(N0 > N1 ? N0 : N1);  // 100000
  int P = in_sizes[2] / 2;  // 16384
  int M = in_sizes[3];      // 8192

  unsigned* posA = (unsigned*)d_ws;            // [P][16] u32 (bf16 pairs)
  unsigned* posB = posA + (size_t)P * 16;
  unsigned* subA = posB + (size_t)P * 16;      // [M][16]
  unsigned* subB = subA + (size_t)M * 16;
  float* rn0 = (float*)(subB + (size_t)M * 16);
  float* rn1 = rn0 + P;
  float* cnb0 = rn1 + P;
  float* cnb1 = cnb0 + M;
  unsigned* mp0 = (unsigned*)(cnb1 + M);       // ---- 0xFF fill region start
  unsigned* mp1 = mp0 + P;
  unsigned long long* table = (unsigned long long*)(mp1 + P);
  float* accum = (float*)(table + HASH_SIZE);  // ---- zero region
  unsigned* tickets = (unsigned*)(accum + 8);
  unsigned* donecnt = tickets + 256;

  int fillWords = 2 * P + 2 * HASH_SIZE;  // u32 words in 0xFF region
  int nvec4 = fillWords / 4;
  int nzero = 8 + 256 + 8;  // accum + tickets + donecnt (+pad); stride loop covers >256
  init_ws<<<(nvec4 + 255) / 256, 256, 0, stream>>>((uint4*)mp0, nvec4, (unsigned*)accum, nzero);

  int nPosB = P / 64, nSubB = M / 64;
  gather_all<<<nPosB + 2 * nSubB, 64, 0, stream>>>(
      F0, F1, matches, sel0, sel1, posA, posB, subA, subB, rn0, rn1, cnb0, cnb1,
      table, accum, hash_seed, P, M);

  int halfgrid = (P / 128) * 8;  // 1024
  minkernel<<<2 * halfgrid, 256, 0, stream>>>(
      posA, posB, subA, subB, cnb0, cnb1, rn0, rn1, matches, sel0, sel1, table,
      mp0, mp1, accum, tickets, donecnt, (float*)d_out, hash_seed, halfgrid, P);
}